// Round 8
// baseline (120.098 us; speedup 1.0000x reference)
//
#include <hip/hip_runtime.h>

#define G_    32
#define N_    128
#define NP1_  129
#define H_    32
#define EAD_  16
#define MAXD_ 5
#define NE_   65536
#define NPTH_ 1048576
#define HALF_ 64     // j-chunk per mix block

// round-to-nearest-even f32 -> bf16 bits
static __device__ __forceinline__ unsigned int f2bf(float f) {
  unsigned int u = __float_as_uint(f);
  u += 0x7fffu + ((u >> 16) & 1u);
  return u >> 16;
}

// ---------------------------------------------------------------------------
// Kernel 1: edge encoder into compact eaval[NE][H]; edge_map[(g,i,j)] = e+1.
// ---------------------------------------------------------------------------
__global__ __launch_bounds__(256) void edge_encode_kernel(
    const float* __restrict__ edge_attr,    // [NE][16]
    const int*   __restrict__ edge_index,   // [3][NE]
    const float* __restrict__ edge_enc_w,   // [H][16]
    float*       __restrict__ eaval,        // [NE][H]
    int*         __restrict__ edge_map) {   // [G][N][N], e+1 (0 = empty)
  int t = blockIdx.x * blockDim.x + threadIdx.x;
  if (t >= NE_ * H_) return;
  int e = t >> 5;
  int h = t & 31;
  const float* ea = edge_attr + e * EAD_;
  const float* w  = edge_enc_w + h * EAD_;
  float s = 0.f;
#pragma unroll
  for (int k = 0; k < EAD_; ++k) s += ea[k] * w[k];
  eaval[t] = s;
  if (h == 0) {
    int g = edge_index[e];
    int i = edge_index[NE_ + e];
    int j = edge_index[2 * NE_ + e];
    edge_map[(g * N_ + i) * N_ + j] = e + 1;
  }
}

// ---------------------------------------------------------------------------
// Kernel 2: destination-organized path scatter. 1 thread per path; probe
// edge_map (2MB, L2); survivors store e+1 into slot[G][N][N][D] (unique).
// ---------------------------------------------------------------------------
__global__ __launch_bounds__(256) void path_scatter_kernel(
    const int* __restrict__ path_index,     // [6][NPTH]
    const int* __restrict__ edge_map,       // [G][N][N]
    int*       __restrict__ slot) {         // [G][N][N][MAXD]
  int p = blockIdx.x * blockDim.x + threadIdx.x;
  int pg = path_index[p];
  int pi = path_index[NPTH_ + p];
  int pj = path_index[2 * NPTH_ + p];
  int pd = path_index[3 * NPTH_ + p];
  int ps = path_index[4 * NPTH_ + p];
  int pt = path_index[5 * NPTH_ + p];
  int m = edge_map[(pg * N_ + ps) * N_ + pt];
  if (m) {
    slot[((pg * N_ + pi) * N_ + pj) * MAXD_ + pd] = m;
  }
}

// ---------------------------------------------------------------------------
// Kernel 3: mix over a half-row (64 cells). One block per (g, i, half).
// Phase 0: coalesced scan of 320 slot ints -> LDS queue (jl<<19|d<<16|e).
// Phase A: 8 lane-groups drain queue (~2 items each): uniform eaval row x
//          Wd (L1) -> LDS float atomicAdd (2-way on wave64 = free).
// Phase A2: val = spe[sp[j]] + val*inv  (h fast -> coalesced spe rows).
// Phase W: pack bf16 pairs -> valmid[g][i][h][j] (contiguous per h).
// ---------------------------------------------------------------------------
__global__ __launch_bounds__(256) void mix_half_kernel(
    const int*   __restrict__ slot,         // [G][N][N][MAXD]
    const int*   __restrict__ spatial_pos,  // [G][N][N]
    const float* __restrict__ spe,          // [512][H]
    const float* __restrict__ eaval,        // [NE][H]
    const float* __restrict__ Wdis,         // [d][h][k]
    unsigned short* __restrict__ valmid) {  // [G*N][H][N] bf16
  __shared__ float lds_val[HALF_ * 33];
  __shared__ int   q[HALF_ * MAXD_];
  __shared__ int   q_cnt;

  int blk = blockIdx.x;
  int c   = blk & 1;
  int gi  = blk >> 1;              // g*N + i
  int j0  = c * HALF_;
  int tid = threadIdx.x;

  for (int t = tid; t < HALF_ * 33; t += 256) lds_val[t] = 0.f;
  if (tid == 0) q_cnt = 0;
  __syncthreads();

  // phase 0: 320 contiguous ints
  const int* srow = slot + ((size_t)gi * N_ + j0) * MAXD_;
  for (int f = tid; f < HALF_ * MAXD_; f += 256) {
    int m = srow[f];
    if (m) {
      int jl = f / MAXD_;
      int d  = f - jl * MAXD_;
      int idx = atomicAdd(&q_cnt, 1);           // LDS atomic
      q[idx] = (jl << 19) | (d << 16) | (m - 1);
    }
  }
  __syncthreads();
  int cnt = q_cnt;

  // phase A
  int grp  = tid >> 5;
  int lane = tid & 31;
  for (int s = grp; s < cnt; s += 8) {
    int ent = q[s];
    int jl = ent >> 19;
    int d  = (ent >> 16) & 7;
    int e  = ent & 0xFFFF;
    const float* ea = eaval + (size_t)e * H_;   // group-uniform row
    const float* Wd = Wdis + d * (H_ * H_);     // 20KB, L1-resident
    float v0 = 0.f, v1 = 0.f, v2 = 0.f, v3 = 0.f;
#pragma unroll
    for (int h = 0; h < H_; h += 4) {
      v0 += ea[h + 0] * Wd[(h + 0) * H_ + lane];
      v1 += ea[h + 1] * Wd[(h + 1) * H_ + lane];
      v2 += ea[h + 2] * Wd[(h + 2) * H_ + lane];
      v3 += ea[h + 3] * Wd[(h + 3) * H_ + lane];
    }
    atomicAdd(&lds_val[jl * 33 + lane], (v0 + v1) + (v2 + v3));
  }
  __syncthreads();

  // phase A2: spe + normalizer (h fast -> coalesced spe)
  const int* sp_row = spatial_pos + (size_t)gi * N_ + j0;
  for (int t = tid; t < HALF_ * H_; t += 256) {
    int jl = t >> 5;
    int h  = t & 31;
    int s = sp_row[jl];                         // group-uniform
    int s2 = (s == 0) ? 1 : s;
    s2 = (s2 > 1) ? s2 - 1 : s2;
    s2 = (s2 > MAXD_) ? MAXD_ : s2;
    float inv = (s2 == 1) ? 1.0f
              : (s2 == 2) ? 0.5f
              : (s2 == 3) ? (1.0f / 3.0f)
              : (s2 == 4) ? 0.25f : 0.2f;
    lds_val[jl * 33 + h] = spe[s * H_ + h] + lds_val[jl * 33 + h] * inv;
  }
  __syncthreads();

  // phase W: pack 2 j's per thread, contiguous 4B stores per h-row
  unsigned short* vbase = valmid + ((size_t)gi * H_) * N_ + j0;
  for (int u = tid; u < H_ * (HALF_ / 2); u += 256) {
    int h  = u >> 5;
    int jp = u & 31;
    int jl = jp * 2;
    unsigned int lo = f2bf(lds_val[jl * 33 + h]);
    unsigned int hi = f2bf(lds_val[(jl + 1) * 33 + h]);
    *(unsigned int*)(vbase + (size_t)h * N_ + jl) = lo | (hi << 16);
  }
}

// ---------------------------------------------------------------------------
// Kernel 4: pure streaming assembly. No LDS, no barriers.
// out[g][h][a][b] = 2*ab[g][a][b] + (a==0||b==0 ? virt[h]
//                                    : bf16->f32 valmid[g][a-1][h][b-1])
// ---------------------------------------------------------------------------
__global__ __launch_bounds__(256) void stream_out_kernel(
    const float* __restrict__ attn_bias,      // [G][129][129]
    const float* __restrict__ virt,           // [H]
    const unsigned short* __restrict__ valmid,// [G*N][H][N] bf16
    float* __restrict__ out) {                // [G][H][129][129]
  const int PLANE = NP1_ * NP1_;              // 16641
  const int TOT = G_ * H_ * PLANE;
  int stride = gridDim.x * blockDim.x;
  for (int idx = blockIdx.x * blockDim.x + threadIdx.x; idx < TOT;
       idx += stride) {
    int gh = idx / PLANE;                     // const-div -> magic mul
    int r  = idx - gh * PLANE;
    int a  = r / NP1_;
    int b  = r - a * NP1_;
    int g  = gh >> 5;
    int h  = gh & 31;
    float base = 2.f * attn_bias[g * PLANE + r];   // coalesced, L2-reused
    float add;
    if (a == 0 || b == 0) {
      add = virt[h];                          // L1
    } else {
      unsigned short v =
          valmid[((size_t)(g * N_ + (a - 1)) * H_ + h) * N_ + (b - 1)];
      add = __uint_as_float((unsigned int)v << 16);
    }
    out[idx] = base + add;
  }
}

// ---------------------------------------------------------------------------
extern "C" void kernel_launch(void* const* d_in, const int* in_sizes, int n_in,
                              void* d_out, int out_size, void* d_ws, size_t ws_size,
                              hipStream_t stream) {
  const float* attn_bias   = (const float*)d_in[0];
  const int*   spatial_pos = (const int*)d_in[1];
  const int*   edge_index  = (const int*)d_in[2];
  const float* edge_attr   = (const float*)d_in[3];
  const int*   path_index  = (const int*)d_in[4];
  const float* edge_enc_w  = (const float*)d_in[5];
  const float* spe         = (const float*)d_in[6];
  const float* virt        = (const float*)d_in[7];
  const float* edge_dis    = (const float*)d_in[8];
  float* out = (float*)d_out;

  const size_t SLOT_ELEMS = (size_t)G_ * N_ * N_ * MAXD_;  // 2.62M ints
  const size_t MAP_ELEMS  = (size_t)G_ * N_ * N_;          // 512K ints
  const size_t EAV_ELEMS  = (size_t)NE_ * H_;              // 2.1M floats

  int*            slot     = (int*)d_ws;
  int*            edge_map = slot + SLOT_ELEMS;
  float*          eaval    = (float*)(edge_map + MAP_ELEMS);
  unsigned short* valmid   = (unsigned short*)(eaval + EAV_ELEMS);

  // zero slot + edge_map (contiguous, 12.6MB); valmid fully overwritten
  hipMemsetAsync(slot, 0, (SLOT_ELEMS + MAP_ELEMS) * sizeof(int), stream);

  // edge encoder + map
  edge_encode_kernel<<<(NE_ * H_ + 255) / 256, 256, 0, stream>>>(
      edge_attr, edge_index, edge_enc_w, eaval, edge_map);
  // destination-organized path scatter
  path_scatter_kernel<<<NPTH_ / 256, 256, 0, stream>>>(
      path_index, edge_map, slot);
  // per-half-row mix -> bf16 valmid
  mix_half_kernel<<<G_ * N_ * 2, 256, 0, stream>>>(
      slot, spatial_pos, spe, eaval, edge_dis, valmid);
  // pure streaming output
  stream_out_kernel<<<2048, 256, 0, stream>>>(
      attn_bias, virt, valmid, out);
}